// Round 3
// baseline (1150.164 us; speedup 1.0000x reference)
//
#include <hip/hip_runtime.h>
#include <hip/hip_bf16.h>

typedef unsigned short u16;
typedef __attribute__((ext_vector_type(8))) short short8;
typedef __attribute__((ext_vector_type(4))) short s4;
typedef __attribute__((ext_vector_type(4))) float floatx4;

__device__ __forceinline__ float lrelu(float x) { return x > 0.f ? x : 0.01f * x; }

__device__ __forceinline__ short bf16bits(float v) {
  __hip_bfloat16 t = __float2bfloat16(v);
  return *reinterpret_cast<short*>(&t);
}

// ---------------------------------------------------------------------------
// Transpose+convert W[K][N] (row-major f32) -> Wt[N][K] (row-major bf16).
// ---------------------------------------------------------------------------
__global__ __launch_bounds__(256) void transpose_f32_bf16(const float* __restrict__ W,
                                                          u16* __restrict__ Wt,
                                                          int K, int N) {
  __shared__ u16 tile[32][33];
  const int tx = threadIdx.x & 31;
  const int ty = threadIdx.x >> 5;  // 0..7
  const int n0 = blockIdx.x * 32;
  const int k0 = blockIdx.y * 32;
  for (int i = ty; i < 32; i += 8) {
    int k = k0 + i, n = n0 + tx;
    tile[i][tx] = (k < K && n < N) ? (u16)bf16bits(W[(size_t)k * N + n]) : (u16)0;
  }
  __syncthreads();
  for (int i = ty; i < 32; i += 8) {
    int n = n0 + i, k = k0 + tx;
    if (n < N && k < K) Wt[(size_t)n * K + k] = tile[tx][i];
  }
}

// ---------------------------------------------------------------------------
// Fused 3-layer MLP on a 64-row block. Activations f32 in global, bf16 in LDS.
//   h1 = lrelu(A0 @ W1t^T + b1)   [64][512]  -> LDS (bf16)
//   h2 = lrelu(h1 @ W2t^T + b2)   [64][512]  -> LDS (bf16)
//   y  = lrelu(h2 @ W3t^T + b3)   [64][256]  (f32)
// MODE 1: atomicAdd y into segOut[dagIds[row]][*] (f32)
// MODE 0: store y f32 to C[row][*]
// 512 threads = 8 waves; wave w owns n-slice [w*64,w*64+64) (layers 1-2),
// [w*32,w*32+32) (layer 3). Swapped-operand MFMA: a-frag = weight rows,
// b-frag = activation rows. D[n_out][act_row]: n_out=quad*4+reg, act=lane&15.
// LDS: H1[64][520] + H2[64][520] bf16 = 133120 B (dynamic).
// ---------------------------------------------------------------------------
#define H_PITCH 520
#define FUSED_LDS (64 * H_PITCH * 2 * 2)

template <int K1, int MODE>
__global__ __launch_bounds__(512, 2) void fused3(
    const float* __restrict__ A0,  // [M][K1] f32
    const u16* __restrict__ W1t,   // [512][K1] bf16
    const u16* __restrict__ W2t,   // [512][512] bf16
    const u16* __restrict__ W3t,   // [256][512] bf16
    const float* __restrict__ b1,
    const float* __restrict__ b2,
    const float* __restrict__ b3,
    float* __restrict__ segOut, const int* __restrict__ dagIds,
    float* __restrict__ C, int M) {
  extern __shared__ __align__(16) char ldsbuf[];
  u16* H1 = (u16*)ldsbuf;
  u16* H2 = (u16*)(ldsbuf + 64 * H_PITCH * 2);

  const int tid  = threadIdx.x;
  const int wv   = tid >> 6;   // 0..7
  const int lane = tid & 63;
  const int m16  = lane & 15;
  const int quad = lane >> 4;  // 0..3
  const int row0 = blockIdx.x * 64;

  int grow[4];
#pragma unroll
  for (int mi = 0; mi < 4; ++mi) {
    int r = row0 + mi * 16 + m16;
    grow[mi] = r < M ? r : (M - 1);
  }

  // ---------------- layer 1: N=512, K=K1, A from global f32 ----------------
  {
    const int n0 = wv * 64;
    floatx4 acc[4][4];
#pragma unroll
    for (int i = 0; i < 4; i++)
#pragma unroll
      for (int j = 0; j < 4; j++) { floatx4 z = {0.f,0.f,0.f,0.f}; acc[i][j] = z; }

    for (int k0 = 0; k0 < K1; k0 += 32) {
      short8 af[4], bx[4];
#pragma unroll
      for (int ni = 0; ni < 4; ++ni)
        af[ni] = *(const short8*)(W1t + (size_t)(n0 + ni * 16 + m16) * K1 + k0 + quad * 8);
#pragma unroll
      for (int mi = 0; mi < 4; ++mi) {
        const floatx4* p = (const floatx4*)(A0 + (size_t)grow[mi] * K1 + k0 + quad * 8);
        floatx4 x0 = p[0], x1 = p[1];
        short8 b;
#pragma unroll
        for (int r = 0; r < 4; ++r) { b[r] = bf16bits(x0[r]); b[4 + r] = bf16bits(x1[r]); }
        bx[mi] = b;
      }
#pragma unroll
      for (int ni = 0; ni < 4; ++ni)
#pragma unroll
        for (int mi = 0; mi < 4; ++mi)
          acc[ni][mi] = __builtin_amdgcn_mfma_f32_16x16x32_bf16(af[ni], bx[mi], acc[ni][mi], 0, 0, 0);
    }
#pragma unroll
    for (int ni = 0; ni < 4; ++ni) {
      const int nb = n0 + ni * 16 + quad * 4;
      float bb[4];
#pragma unroll
      for (int r = 0; r < 4; ++r) bb[r] = b1[nb + r];
#pragma unroll
      for (int mi = 0; mi < 4; ++mi) {
        s4 h;
#pragma unroll
        for (int r = 0; r < 4; ++r) h[r] = bf16bits(lrelu(acc[ni][mi][r] + bb[r]));
        *(s4*)&H1[(mi * 16 + m16) * H_PITCH + nb] = h;
      }
    }
  }
  __syncthreads();

  // ---------------- layer 2: N=512, K=512, A from LDS H1 (bf16) ----------------
  {
    const int n0 = wv * 64;
    floatx4 acc[4][4];
#pragma unroll
    for (int i = 0; i < 4; i++)
#pragma unroll
      for (int j = 0; j < 4; j++) { floatx4 z = {0.f,0.f,0.f,0.f}; acc[i][j] = z; }

    for (int k0 = 0; k0 < 512; k0 += 32) {
      short8 af[4], bx[4];
#pragma unroll
      for (int ni = 0; ni < 4; ++ni)
        af[ni] = *(const short8*)(W2t + (size_t)(n0 + ni * 16 + m16) * 512 + k0 + quad * 8);
#pragma unroll
      for (int mi = 0; mi < 4; ++mi)
        bx[mi] = *(const short8*)&H1[(mi * 16 + m16) * H_PITCH + k0 + quad * 8];
#pragma unroll
      for (int ni = 0; ni < 4; ++ni)
#pragma unroll
        for (int mi = 0; mi < 4; ++mi)
          acc[ni][mi] = __builtin_amdgcn_mfma_f32_16x16x32_bf16(af[ni], bx[mi], acc[ni][mi], 0, 0, 0);
    }
#pragma unroll
    for (int ni = 0; ni < 4; ++ni) {
      const int nb = n0 + ni * 16 + quad * 4;
      float bb[4];
#pragma unroll
      for (int r = 0; r < 4; ++r) bb[r] = b2[nb + r];
#pragma unroll
      for (int mi = 0; mi < 4; ++mi) {
        s4 h;
#pragma unroll
        for (int r = 0; r < 4; ++r) h[r] = bf16bits(lrelu(acc[ni][mi][r] + bb[r]));
        *(s4*)&H2[(mi * 16 + m16) * H_PITCH + nb] = h;
      }
    }
  }
  __syncthreads();

  // ---------------- layer 3: N=256, K=512, A from LDS H2 (bf16) ----------------
  {
    const int n0 = wv * 32;
    floatx4 acc[2][4];
#pragma unroll
    for (int i = 0; i < 2; i++)
#pragma unroll
      for (int j = 0; j < 4; j++) { floatx4 z = {0.f,0.f,0.f,0.f}; acc[i][j] = z; }

    for (int k0 = 0; k0 < 512; k0 += 32) {
      short8 af[2], bx[4];
#pragma unroll
      for (int ni = 0; ni < 2; ++ni)
        af[ni] = *(const short8*)(W3t + (size_t)(n0 + ni * 16 + m16) * 512 + k0 + quad * 8);
#pragma unroll
      for (int mi = 0; mi < 4; ++mi)
        bx[mi] = *(const short8*)&H2[(mi * 16 + m16) * H_PITCH + k0 + quad * 8];
#pragma unroll
      for (int ni = 0; ni < 2; ++ni)
#pragma unroll
        for (int mi = 0; mi < 4; ++mi)
          acc[ni][mi] = __builtin_amdgcn_mfma_f32_16x16x32_bf16(af[ni], bx[mi], acc[ni][mi], 0, 0, 0);
    }

    float bb[2][4];
#pragma unroll
    for (int ni = 0; ni < 2; ++ni)
#pragma unroll
      for (int r = 0; r < 4; ++r)
        bb[ni][r] = b3[n0 + ni * 16 + quad * 4 + r];

#pragma unroll
    for (int mi = 0; mi < 4; ++mi) {
      const int r0 = row0 + mi * 16 + m16;
      if (r0 < M) {
        if (MODE == 1) {
          const int dg = dagIds[r0];
          float* dst = segOut + (size_t)dg * 256;
#pragma unroll
          for (int ni = 0; ni < 2; ++ni)
#pragma unroll
            for (int r = 0; r < 4; ++r)
              atomicAdd(dst + n0 + ni * 16 + quad * 4 + r,
                        lrelu(acc[ni][mi][r] + bb[ni][r]));
        } else {
#pragma unroll
          for (int ni = 0; ni < 2; ++ni) {
            floatx4 h;
#pragma unroll
            for (int r = 0; r < 4; ++r)
              h[r] = lrelu(acc[ni][mi][r] + bb[ni][r]);
            *(floatx4*)&C[(size_t)r0 * 256 + n0 + ni * 16 + quad * 4] = h;
          }
        }
      }
    }
  }
}

// ---------------------------------------------------------------------------
// s2[j] = sum_d mask[d] * g3[d][j]   (all f32)
// ---------------------------------------------------------------------------
__global__ __launch_bounds__(256) void s2_reduce(const float* __restrict__ mask,
                                                 const float* __restrict__ g3,
                                                 float* __restrict__ out,
                                                 int numDags, int outDim, int outOff) {
  const int j = threadIdx.x;
  float acc = 0.f;
  for (int d = 0; d < numDags; ++d)
    acc += mask[d] * g3[(size_t)d * outDim + j];
  out[outOff + j] = acc;
}

extern "C" void kernel_launch(void* const* d_in, const int* in_sizes, int n_in,
                              void* d_out, int out_size, void* d_ws, size_t ws_size,
                              hipStream_t stream) {
  (void)in_sizes; (void)n_in; (void)out_size; (void)ws_size;
  constexpr int N_   = 100000;
  constexpr int IND  = 128;
  constexpr int H1D  = 512;
  constexpr int H2D  = 512;
  constexpr int OUTD = 256;
  constexpr int NDAG = 2000;

  const float* X    = (const float*)d_in[0];
  const int*   dag  = (const int*)d_in[1];
  const float* mask = (const float*)d_in[2];
  const float* W1 = (const float*)d_in[3];
  const float* b1 = (const float*)d_in[4];
  const float* W2 = (const float*)d_in[5];
  const float* b2 = (const float*)d_in[6];
  const float* W3 = (const float*)d_in[7];
  const float* b3 = (const float*)d_in[8];
  const float* W4 = (const float*)d_in[9];
  const float* b4 = (const float*)d_in[10];
  const float* W5 = (const float*)d_in[11];
  const float* b5 = (const float*)d_in[12];
  const float* W6 = (const float*)d_in[13];
  const float* b6 = (const float*)d_in[14];

  char* ws = (char*)d_ws;
  auto alloc = [&](size_t bytes) {
    char* p = ws;
    ws += (bytes + 255) & ~(size_t)255;
    return p;
  };
  u16* W1t = (u16*)alloc((size_t)H1D * IND * 2);
  u16* W2t = (u16*)alloc((size_t)H2D * H1D * 2);
  u16* W3t = (u16*)alloc((size_t)OUTD * H2D * 2);
  u16* W4t = (u16*)alloc((size_t)H1D * OUTD * 2);
  u16* W5t = (u16*)alloc((size_t)H2D * H1D * 2);
  u16* W6t = (u16*)alloc((size_t)OUTD * H2D * 2);
  float* g3 = (float*)alloc((size_t)NDAG * OUTD * 4);

  float* out = (float*)d_out;
  float* s1  = out;                       // [2000][256] f32, output 0
  const int s2Off = NDAG * OUTD;          // output 1 offset

  // allow >64KB dynamic LDS (idempotent host-side attribute; capture-safe)
  hipFuncSetAttribute(reinterpret_cast<const void*>(&fused3<IND, 1>),
                      hipFuncAttributeMaxDynamicSharedMemorySize, FUSED_LDS);
  hipFuncSetAttribute(reinterpret_cast<const void*>(&fused3<OUTD, 0>),
                      hipFuncAttributeMaxDynamicSharedMemorySize, FUSED_LDS);

  // zero the segment-sum accumulator (= output 0 region; harness poisons it)
  hipMemsetAsync(s1, 0, (size_t)NDAG * OUTD * 4, stream);

  // weight transposes+convert: W[K][N] f32 -> Wt[N][K] bf16; grid (N/32, K/32)
  transpose_f32_bf16<<<dim3(H1D / 32, IND / 32), 256, 0, stream>>>(W1, W1t, IND, H1D);
  transpose_f32_bf16<<<dim3(H2D / 32, H1D / 32), 256, 0, stream>>>(W2, W2t, H1D, H2D);
  transpose_f32_bf16<<<dim3(OUTD / 32, H2D / 32), 256, 0, stream>>>(W3, W3t, H2D, OUTD);
  transpose_f32_bf16<<<dim3(H1D / 32, OUTD / 32), 256, 0, stream>>>(W4, W4t, OUTD, H1D);
  transpose_f32_bf16<<<dim3(H2D / 32, H1D / 32), 256, 0, stream>>>(W5, W5t, H1D, H2D);
  transpose_f32_bf16<<<dim3(OUTD / 32, H2D / 32), 256, 0, stream>>>(W6, W6t, H2D, OUTD);

  // fused node stack + segment-sum (f32 atomics straight into output 0)
  fused3<IND, 1><<<(N_ + 63) / 64, 512, FUSED_LDS, stream>>>(
      X, W1t, W2t, W3t, b1, b2, b3, s1, dag, nullptr, N_);

  // fused global stack: reads s1 (f32, from d_out), writes g3 (f32)
  fused3<OUTD, 0><<<(NDAG + 63) / 64, 512, FUSED_LDS, stream>>>(
      s1, W4t, W5t, W6t, b4, b5, b6, nullptr, nullptr, g3, NDAG);

  // s2 = mask @ g3  -> output 1
  s2_reduce<<<1, 256, 0, stream>>>(mask, g3, out, NDAG, OUTD, s2Off);
}

// Round 4
// 707.603 us; speedup vs baseline: 1.6254x; 1.6254x over previous
//
#include <hip/hip_runtime.h>
#include <hip/hip_bf16.h>

typedef unsigned short u16;
typedef __attribute__((ext_vector_type(8))) short short8;
typedef __attribute__((ext_vector_type(4))) short s4;
typedef __attribute__((ext_vector_type(4))) float floatx4;

__device__ __forceinline__ float lrelu(float x) { return x > 0.f ? x : 0.01f * x; }

__device__ __forceinline__ short bf16bits(float v) {
  __hip_bfloat16 t = __float2bfloat16(v);
  return *reinterpret_cast<short*>(&t);
}

__device__ __forceinline__ short8 pack8(floatx4 x0, floatx4 x1) {
  short8 b;
#pragma unroll
  for (int r = 0; r < 4; ++r) { b[r] = bf16bits(x0[r]); b[4 + r] = bf16bits(x1[r]); }
  return b;
}

// ---------------------------------------------------------------------------
// Transpose+convert W[K][N] (row-major f32) -> Wt[N][K] (row-major bf16).
// ---------------------------------------------------------------------------
__global__ __launch_bounds__(256) void transpose_f32_bf16(const float* __restrict__ W,
                                                          u16* __restrict__ Wt,
                                                          int K, int N) {
  __shared__ u16 tile[32][33];
  const int tx = threadIdx.x & 31;
  const int ty = threadIdx.x >> 5;
  const int n0 = blockIdx.x * 32;
  const int k0 = blockIdx.y * 32;
  for (int i = ty; i < 32; i += 8) {
    int k = k0 + i, n = n0 + tx;
    tile[i][tx] = (k < K && n < N) ? (u16)bf16bits(W[(size_t)k * N + n]) : (u16)0;
  }
  __syncthreads();
  for (int i = ty; i < 32; i += 8) {
    int n = n0 + i, k = k0 + tx;
    if (n < N && k < K) Wt[(size_t)n * K + k] = tile[tx][i];
  }
}

// ---------------------------------------------------------------------------
// Fused 3-layer MLP on a 32-row block. Activations f32 global, bf16 in LDS.
//   h1 = lrelu(A0 @ W1t^T + b1)  [32][512] -> LDS
//   h2 = lrelu(h1 @ W2t^T + b2)  [32][512] -> LDS
//   y  = lrelu(h2 @ W3t^T + b3)  [32][256]
// MODE 1: atomicAdd y into segOut[dagIds[row]][*]; MODE 0: store f32 C.
// 512 thr = 8 waves. Layers 1-2: wave w owns cols [w*64,w*64+64); layer 3:
// [w*32,w*32+32). Swapped-operand MFMA: a=weight rows, b=activation rows.
// D[n][m]: n=quad*4+reg, m=lane&15.
// LDS = 2*32*520*2 = 66560 B -> 2 blocks/CU (16 waves) for latency hiding.
// Weight frags register-prefetched one k-step ahead (L2 latency overlap).
// ---------------------------------------------------------------------------
#define ROWS 32
#define H_PITCH 520
#define FUSED_LDS (ROWS * H_PITCH * 2 * 2)

template <int K1, int MODE>
__global__ __launch_bounds__(512, 4) void fused3(
    const float* __restrict__ A0,  // [M][K1] f32
    const u16* __restrict__ W1t,   // [512][K1] bf16
    const u16* __restrict__ W2t,   // [512][512] bf16
    const u16* __restrict__ W3t,   // [256][512] bf16
    const float* __restrict__ b1,
    const float* __restrict__ b2,
    const float* __restrict__ b3,
    float* __restrict__ segOut, const int* __restrict__ dagIds,
    float* __restrict__ C, int M) {
  extern __shared__ __align__(16) char ldsbuf[];
  u16* H1 = (u16*)ldsbuf;
  u16* H2 = H1 + ROWS * H_PITCH;

  const int tid  = threadIdx.x;
  const int wv   = tid >> 6;   // 0..7
  const int lane = tid & 63;
  const int m16  = lane & 15;
  const int quad = lane >> 4;  // 0..3
  const int row0 = blockIdx.x * ROWS;

  int grow[2];
#pragma unroll
  for (int mi = 0; mi < 2; ++mi) {
    int r = row0 + mi * 16 + m16;
    grow[mi] = r < M ? r : (M - 1);
  }

  // ---------------- layer 1: N=512, K=K1, A from global f32 ----------------
  {
    const int n0 = wv * 64;
    const u16* wp[4];
#pragma unroll
    for (int ni = 0; ni < 4; ++ni)
      wp[ni] = W1t + (size_t)(n0 + ni * 16 + m16) * K1 + quad * 8;
    const float* ap[2];
#pragma unroll
    for (int mi = 0; mi < 2; ++mi)
      ap[mi] = A0 + (size_t)grow[mi] * K1 + quad * 8;

    floatx4 acc[4][2];
#pragma unroll
    for (int i = 0; i < 4; i++)
#pragma unroll
      for (int j = 0; j < 2; j++) { floatx4 z = {0.f,0.f,0.f,0.f}; acc[i][j] = z; }

#pragma unroll
    for (int k0 = 0; k0 < K1; k0 += 32) {
      short8 af[4], bx[2];
#pragma unroll
      for (int ni = 0; ni < 4; ++ni) af[ni] = *(const short8*)(wp[ni] + k0);
#pragma unroll
      for (int mi = 0; mi < 2; ++mi) {
        floatx4 x0 = *(const floatx4*)(ap[mi] + k0);
        floatx4 x1 = *(const floatx4*)(ap[mi] + k0 + 4);
        bx[mi] = pack8(x0, x1);
      }
#pragma unroll
      for (int ni = 0; ni < 4; ++ni)
#pragma unroll
        for (int mi = 0; mi < 2; ++mi)
          acc[ni][mi] = __builtin_amdgcn_mfma_f32_16x16x32_bf16(af[ni], bx[mi], acc[ni][mi], 0, 0, 0);
    }
#pragma unroll
    for (int ni = 0; ni < 4; ++ni) {
      const int nb = n0 + ni * 16 + quad * 4;
      floatx4 bb = *(const floatx4*)&b1[nb];
#pragma unroll
      for (int mi = 0; mi < 2; ++mi) {
        s4 h;
#pragma unroll
        for (int r = 0; r < 4; ++r) h[r] = bf16bits(lrelu(acc[ni][mi][r] + bb[r]));
        *(s4*)&H1[(mi * 16 + m16) * H_PITCH + nb] = h;
      }
    }
  }
  __syncthreads();

  // ---------------- layer 2: N=512, K=512, A from LDS H1 ----------------
  {
    const int n0 = wv * 64;
    const u16* wp[4];
#pragma unroll
    for (int ni = 0; ni < 4; ++ni)
      wp[ni] = W2t + (size_t)(n0 + ni * 16 + m16) * 512 + quad * 8;
    const u16* hp[2];
#pragma unroll
    for (int mi = 0; mi < 2; ++mi)
      hp[mi] = H1 + (mi * 16 + m16) * H_PITCH + quad * 8;

    floatx4 acc[4][2];
#pragma unroll
    for (int i = 0; i < 4; i++)
#pragma unroll
      for (int j = 0; j < 2; j++) { floatx4 z = {0.f,0.f,0.f,0.f}; acc[i][j] = z; }

    short8 afn[4];
#pragma unroll
    for (int ni = 0; ni < 4; ++ni) afn[ni] = *(const short8*)wp[ni];

#pragma unroll 1
    for (int k0 = 0; k0 < 512; k0 += 32) {
      short8 af[4];
#pragma unroll
      for (int ni = 0; ni < 4; ++ni) af[ni] = afn[ni];
      if (k0 + 32 < 512) {
#pragma unroll
        for (int ni = 0; ni < 4; ++ni) afn[ni] = *(const short8*)(wp[ni] + k0 + 32);
      }
      short8 bx[2];
#pragma unroll
      for (int mi = 0; mi < 2; ++mi) bx[mi] = *(const short8*)(hp[mi] + k0);
#pragma unroll
      for (int ni = 0; ni < 4; ++ni)
#pragma unroll
        for (int mi = 0; mi < 2; ++mi)
          acc[ni][mi] = __builtin_amdgcn_mfma_f32_16x16x32_bf16(af[ni], bx[mi], acc[ni][mi], 0, 0, 0);
    }
#pragma unroll
    for (int ni = 0; ni < 4; ++ni) {
      const int nb = n0 + ni * 16 + quad * 4;
      floatx4 bb = *(const floatx4*)&b2[nb];
#pragma unroll
      for (int mi = 0; mi < 2; ++mi) {
        s4 h;
#pragma unroll
        for (int r = 0; r < 4; ++r) h[r] = bf16bits(lrelu(acc[ni][mi][r] + bb[r]));
        *(s4*)&H2[(mi * 16 + m16) * H_PITCH + nb] = h;
      }
    }
  }
  __syncthreads();

  // ---------------- layer 3: N=256, K=512, A from LDS H2 ----------------
  {
    const int n0 = wv * 32;
    const u16* wp[2];
#pragma unroll
    for (int ni = 0; ni < 2; ++ni)
      wp[ni] = W3t + (size_t)(n0 + ni * 16 + m16) * 512 + quad * 8;
    const u16* hp[2];
#pragma unroll
    for (int mi = 0; mi < 2; ++mi)
      hp[mi] = H2 + (mi * 16 + m16) * H_PITCH + quad * 8;

    floatx4 acc[2][2];
#pragma unroll
    for (int i = 0; i < 2; i++)
#pragma unroll
      for (int j = 0; j < 2; j++) { floatx4 z = {0.f,0.f,0.f,0.f}; acc[i][j] = z; }

    short8 afn[2];
#pragma unroll
    for (int ni = 0; ni < 2; ++ni) afn[ni] = *(const short8*)wp[ni];

#pragma unroll 1
    for (int k0 = 0; k0 < 512; k0 += 32) {
      short8 af[2];
#pragma unroll
      for (int ni = 0; ni < 2; ++ni) af[ni] = afn[ni];
      if (k0 + 32 < 512) {
#pragma unroll
        for (int ni = 0; ni < 2; ++ni) afn[ni] = *(const short8*)(wp[ni] + k0 + 32);
      }
      short8 bx[2];
#pragma unroll
      for (int mi = 0; mi < 2; ++mi) bx[mi] = *(const short8*)(hp[mi] + k0);
#pragma unroll
      for (int ni = 0; ni < 2; ++ni)
#pragma unroll
        for (int mi = 0; mi < 2; ++mi)
          acc[ni][mi] = __builtin_amdgcn_mfma_f32_16x16x32_bf16(af[ni], bx[mi], acc[ni][mi], 0, 0, 0);
    }

    floatx4 bb[2];
#pragma unroll
    for (int ni = 0; ni < 2; ++ni)
      bb[ni] = *(const floatx4*)&b3[n0 + ni * 16 + quad * 4];

#pragma unroll
    for (int mi = 0; mi < 2; ++mi) {
      const int r0 = row0 + mi * 16 + m16;
      if (r0 < M) {
        if (MODE == 1) {
          const int dg = dagIds[r0];
          float* dst = segOut + (size_t)dg * 256;
#pragma unroll
          for (int ni = 0; ni < 2; ++ni)
#pragma unroll
            for (int r = 0; r < 4; ++r)
              atomicAdd(dst + n0 + ni * 16 + quad * 4 + r,
                        lrelu(acc[ni][mi][r] + bb[ni][r]));
        } else {
#pragma unroll
          for (int ni = 0; ni < 2; ++ni) {
            floatx4 h;
#pragma unroll
            for (int r = 0; r < 4; ++r) h[r] = lrelu(acc[ni][mi][r] + bb[ni][r]);
            *(floatx4*)&C[(size_t)r0 * 256 + n0 + ni * 16 + quad * 4] = h;
          }
        }
      }
    }
  }
}

// ---------------------------------------------------------------------------
// s2[j] += sum over dag-chunk of mask[d] * g3[d][j]; grid-parallel + atomic.
// ---------------------------------------------------------------------------
__global__ __launch_bounds__(256) void s2_reduce(const float* __restrict__ mask,
                                                 const float* __restrict__ g3,
                                                 float* __restrict__ out,
                                                 int numDags, int outOff) {
  const int j = threadIdx.x;  // 256 cols
  const int chunk = (numDags + gridDim.x - 1) / gridDim.x;
  const int d0 = blockIdx.x * chunk;
  const int d1 = min(d0 + chunk, numDags);
  float acc = 0.f;
  for (int d = d0; d < d1; ++d)
    acc += mask[d] * g3[(size_t)d * 256 + j];
  atomicAdd(out + outOff + j, acc);
}

extern "C" void kernel_launch(void* const* d_in, const int* in_sizes, int n_in,
                              void* d_out, int out_size, void* d_ws, size_t ws_size,
                              hipStream_t stream) {
  (void)in_sizes; (void)n_in; (void)ws_size;
  constexpr int N_   = 100000;
  constexpr int IND  = 128;
  constexpr int H1D  = 512;
  constexpr int H2D  = 512;
  constexpr int OUTD = 256;
  constexpr int NDAG = 2000;

  const float* X    = (const float*)d_in[0];
  const int*   dag  = (const int*)d_in[1];
  const float* mask = (const float*)d_in[2];
  const float* W1 = (const float*)d_in[3];
  const float* b1 = (const float*)d_in[4];
  const float* W2 = (const float*)d_in[5];
  const float* b2 = (const float*)d_in[6];
  const float* W3 = (const float*)d_in[7];
  const float* b3 = (const float*)d_in[8];
  const float* W4 = (const float*)d_in[9];
  const float* b4 = (const float*)d_in[10];
  const float* W5 = (const float*)d_in[11];
  const float* b5 = (const float*)d_in[12];
  const float* W6 = (const float*)d_in[13];
  const float* b6 = (const float*)d_in[14];

  char* ws = (char*)d_ws;
  auto alloc = [&](size_t bytes) {
    char* p = ws;
    ws += (bytes + 255) & ~(size_t)255;
    return p;
  };
  u16* W1t = (u16*)alloc((size_t)H1D * IND * 2);
  u16* W2t = (u16*)alloc((size_t)H2D * H1D * 2);
  u16* W3t = (u16*)alloc((size_t)OUTD * H2D * 2);
  u16* W4t = (u16*)alloc((size_t)H1D * OUTD * 2);
  u16* W5t = (u16*)alloc((size_t)H2D * H1D * 2);
  u16* W6t = (u16*)alloc((size_t)OUTD * H2D * 2);
  float* g3 = (float*)alloc((size_t)NDAG * OUTD * 4);

  float* out = (float*)d_out;
  float* s1  = out;                // [2000][256] f32, output 0
  const int s2Off = NDAG * OUTD;   // output 1 offset

  hipFuncSetAttribute(reinterpret_cast<const void*>(&fused3<IND, 1>),
                      hipFuncAttributeMaxDynamicSharedMemorySize, FUSED_LDS);
  hipFuncSetAttribute(reinterpret_cast<const void*>(&fused3<OUTD, 0>),
                      hipFuncAttributeMaxDynamicSharedMemorySize, FUSED_LDS);

  // zero all of d_out (s1 accumulator + s2 accumulator; harness poisons it)
  hipMemsetAsync(out, 0, (size_t)out_size * 4, stream);

  // weight transposes+convert: W[K][N] f32 -> Wt[N][K] bf16
  transpose_f32_bf16<<<dim3(H1D / 32, IND / 32), 256, 0, stream>>>(W1, W1t, IND, H1D);
  transpose_f32_bf16<<<dim3(H2D / 32, H1D / 32), 256, 0, stream>>>(W2, W2t, H1D, H2D);
  transpose_f32_bf16<<<dim3(OUTD / 32, H2D / 32), 256, 0, stream>>>(W3, W3t, H2D, OUTD);
  transpose_f32_bf16<<<dim3(H1D / 32, OUTD / 32), 256, 0, stream>>>(W4, W4t, OUTD, H1D);
  transpose_f32_bf16<<<dim3(H2D / 32, H1D / 32), 256, 0, stream>>>(W5, W5t, H1D, H2D);
  transpose_f32_bf16<<<dim3(OUTD / 32, H2D / 32), 256, 0, stream>>>(W6, W6t, H2D, OUTD);

  // fused node stack + segment-sum (f32 atomics straight into output 0)
  fused3<IND, 1><<<(N_ + ROWS - 1) / ROWS, 512, FUSED_LDS, stream>>>(
      X, W1t, W2t, W3t, b1, b2, b3, s1, dag, nullptr, N_);

  // fused global stack: reads s1 (f32, from d_out), writes g3 (f32)
  fused3<OUTD, 0><<<(NDAG + ROWS - 1) / ROWS, 512, FUSED_LDS, stream>>>(
      s1, W4t, W5t, W6t, b4, b5, b6, nullptr, nullptr, g3, NDAG);

  // s2 = mask @ g3 -> output 1 (out region pre-zeroed)
  s2_reduce<<<20, 256, 0, stream>>>(mask, g3, out, NDAG, s2Off);
}

// Round 5
// 597.033 us; speedup vs baseline: 1.9265x; 1.1852x over previous
//
#include <hip/hip_runtime.h>
#include <hip/hip_bf16.h>

typedef unsigned short u16;
typedef __attribute__((ext_vector_type(8))) short short8;
typedef __attribute__((ext_vector_type(4))) short s4;
typedef __attribute__((ext_vector_type(4))) float floatx4;

__device__ __forceinline__ float lrelu(float x) { return x > 0.f ? x : 0.01f * x; }

__device__ __forceinline__ short bf16bits(float v) {
  __hip_bfloat16 t = __float2bfloat16(v);
  return *reinterpret_cast<short*>(&t);
}

__device__ __forceinline__ short8 pack8(floatx4 x0, floatx4 x1) {
  short8 b;
#pragma unroll
  for (int r = 0; r < 4; ++r) { b[r] = bf16bits(x0[r]); b[4 + r] = bf16bits(x1[r]); }
  return b;
}

// ---------------------------------------------------------------------------
// Transpose+convert W[K][N] f32 -> Wt[N][K] bf16.
// ---------------------------------------------------------------------------
__global__ __launch_bounds__(256) void transpose_f32_bf16(const float* __restrict__ W,
                                                          u16* __restrict__ Wt,
                                                          int K, int N) {
  __shared__ u16 tile[32][33];
  const int tx = threadIdx.x & 31;
  const int ty = threadIdx.x >> 5;
  const int n0 = blockIdx.x * 32;
  const int k0 = blockIdx.y * 32;
  for (int i = ty; i < 32; i += 8) {
    int k = k0 + i, n = n0 + tx;
    tile[i][tx] = (k < K && n < N) ? (u16)bf16bits(W[(size_t)k * N + n]) : (u16)0;
  }
  __syncthreads();
  for (int i = ty; i < 32; i += 8) {
    int n = n0 + i, k = k0 + tx;
    if (n < N && k < K) Wt[(size_t)n * K + k] = tile[tx][i];
  }
}

// ---------------------------------------------------------------------------
// Counting sort of node ids by dag id (2000 bins).
// ---------------------------------------------------------------------------
__global__ __launch_bounds__(256) void hist_kernel(const int* __restrict__ dag,
                                                   int* __restrict__ hist, int n) {
  int i = blockIdx.x * blockDim.x + threadIdx.x;
  if (i < n) atomicAdd(&hist[dag[i]], 1);
}

// exclusive prefix over 2000 bins; writes offs[] and cursor[] (scatter copy).
__global__ __launch_bounds__(256) void scan_offsets(const int* __restrict__ hist,
                                                    int* __restrict__ cursor) {
  __shared__ int part[256];
  const int t = threadIdx.x;
  const int base = t * 8;
  int loc[8];
  int s = 0;
#pragma unroll
  for (int j = 0; j < 8; ++j) {
    int v = (base + j < 2000) ? hist[base + j] : 0;
    loc[j] = s;
    s += v;
  }
  part[t] = s;
  __syncthreads();
  int val = s;
  for (int off = 1; off < 256; off <<= 1) {
    int tmp = (t >= off) ? part[t - off] : 0;
    __syncthreads();
    val += tmp;
    part[t] = val;
    __syncthreads();
  }
  const int chunkBase = (t == 0) ? 0 : part[t - 1];
#pragma unroll
  for (int j = 0; j < 8; ++j)
    if (base + j < 2000) cursor[base + j] = chunkBase + loc[j];
}

__global__ __launch_bounds__(256) void scatter_kernel(const int* __restrict__ dag,
                                                      int* __restrict__ cursor,
                                                      int* __restrict__ perm,
                                                      int* __restrict__ dsort, int n) {
  int i = blockIdx.x * blockDim.x + threadIdx.x;
  if (i < n) {
    int d = dag[i];
    int p = atomicAdd(&cursor[d], 1);
    perm[p] = i;
    dsort[p] = d;
  }
}

// ---------------------------------------------------------------------------
// Fused 3-layer MLP on a 32-row block (rows dag-sorted via perm in MODE 1).
//   h1 = lrelu(A0 @ W1t^T + b1)  [32][512] -> LDS bf16
//   h2 = lrelu(h1 @ W2t^T + b2)  [32][512] -> LDS bf16
//   y  = lrelu(h2 @ W3t^T + b3)  [32][256] f32
// MODE 1: segmented-reduce y over dag runs in LDS, ~1-2 atomics/(seg,col).
// MODE 0: store y f32 to C.
// 512 thr = 8 waves. Swapped-operand MFMA: a=weight rows, b=activation rows.
// D[n][m]: n=quad*4+reg, m=lane&15.
// LDS: H1[32][520] + H2[32][520] bf16 + dag ids = 66816 B -> 2 blocks/CU.
// ---------------------------------------------------------------------------
#define ROWS 32
#define H_PITCH 520
#define Y_PITCH 260
#define FUSED_LDS (ROWS * H_PITCH * 2 * 2 + 256)

template <int K1, int MODE>
__global__ __launch_bounds__(512, 4) void fused3(
    const float* __restrict__ A0,  // [M][K1] f32
    const u16* __restrict__ W1t,   // [512][K1] bf16
    const u16* __restrict__ W2t,   // [512][512] bf16
    const u16* __restrict__ W3t,   // [256][512] bf16
    const float* __restrict__ b1,
    const float* __restrict__ b2,
    const float* __restrict__ b3,
    float* __restrict__ segOut,
    const int* __restrict__ perm, const int* __restrict__ dsort,
    float* __restrict__ C, int M) {
  extern __shared__ __align__(16) char ldsbuf[];
  u16* H1 = (u16*)ldsbuf;
  u16* H2 = H1 + ROWS * H_PITCH;
  float* Yl = (float*)ldsbuf;                       // reuses H1 region (layer 3)
  int* dagsL = (int*)(ldsbuf + ROWS * H_PITCH * 4); // past H2

  const int tid  = threadIdx.x;
  const int wv   = tid >> 6;
  const int lane = tid & 63;
  const int m16  = lane & 15;
  const int quad = lane >> 4;
  const int row0 = blockIdx.x * ROWS;

  int grow[2];
#pragma unroll
  for (int mi = 0; mi < 2; ++mi) {
    int r = row0 + mi * 16 + m16;
    r = r < M ? r : (M - 1);
    grow[mi] = (MODE == 1) ? perm[r] : r;
  }

  // ---------------- layer 1: N=512, K=K1, A gathered from global f32 -------
  {
    const int n0 = wv * 64;
    const u16* wp[4];
#pragma unroll
    for (int ni = 0; ni < 4; ++ni)
      wp[ni] = W1t + (size_t)(n0 + ni * 16 + m16) * K1 + quad * 8;
    const float* ap[2];
#pragma unroll
    for (int mi = 0; mi < 2; ++mi)
      ap[mi] = A0 + (size_t)grow[mi] * K1 + quad * 8;

    floatx4 acc[4][2];
#pragma unroll
    for (int i = 0; i < 4; i++)
#pragma unroll
      for (int j = 0; j < 2; j++) { floatx4 z = {0.f,0.f,0.f,0.f}; acc[i][j] = z; }

#pragma unroll
    for (int k0 = 0; k0 < K1; k0 += 32) {
      short8 af[4], bx[2];
#pragma unroll
      for (int ni = 0; ni < 4; ++ni) af[ni] = *(const short8*)(wp[ni] + k0);
#pragma unroll
      for (int mi = 0; mi < 2; ++mi) {
        floatx4 x0 = *(const floatx4*)(ap[mi] + k0);
        floatx4 x1 = *(const floatx4*)(ap[mi] + k0 + 4);
        bx[mi] = pack8(x0, x1);
      }
#pragma unroll
      for (int ni = 0; ni < 4; ++ni)
#pragma unroll
        for (int mi = 0; mi < 2; ++mi)
          acc[ni][mi] = __builtin_amdgcn_mfma_f32_16x16x32_bf16(af[ni], bx[mi], acc[ni][mi], 0, 0, 0);
    }
#pragma unroll
    for (int ni = 0; ni < 4; ++ni) {
      const int nb = n0 + ni * 16 + quad * 4;
      floatx4 bb = *(const floatx4*)&b1[nb];
#pragma unroll
      for (int mi = 0; mi < 2; ++mi) {
        s4 h;
#pragma unroll
        for (int r = 0; r < 4; ++r) h[r] = bf16bits(lrelu(acc[ni][mi][r] + bb[r]));
        *(s4*)&H1[(mi * 16 + m16) * H_PITCH + nb] = h;
      }
    }
  }
  __syncthreads();

  // ---------------- layer 2: N=512, K=512, A from LDS H1 ----------------
  {
    const int n0 = wv * 64;
    const u16* wp[4];
#pragma unroll
    for (int ni = 0; ni < 4; ++ni)
      wp[ni] = W2t + (size_t)(n0 + ni * 16 + m16) * 512 + quad * 8;
    const u16* hp[2];
#pragma unroll
    for (int mi = 0; mi < 2; ++mi)
      hp[mi] = H1 + (mi * 16 + m16) * H_PITCH + quad * 8;

    floatx4 acc[4][2];
#pragma unroll
    for (int i = 0; i < 4; i++)
#pragma unroll
      for (int j = 0; j < 2; j++) { floatx4 z = {0.f,0.f,0.f,0.f}; acc[i][j] = z; }

    short8 afn[4];
#pragma unroll
    for (int ni = 0; ni < 4; ++ni) afn[ni] = *(const short8*)wp[ni];

#pragma unroll 1
    for (int k0 = 0; k0 < 512; k0 += 32) {
      short8 af[4];
#pragma unroll
      for (int ni = 0; ni < 4; ++ni) af[ni] = afn[ni];
      if (k0 + 32 < 512) {
#pragma unroll
        for (int ni = 0; ni < 4; ++ni) afn[ni] = *(const short8*)(wp[ni] + k0 + 32);
      }
      short8 bx[2];
#pragma unroll
      for (int mi = 0; mi < 2; ++mi) bx[mi] = *(const short8*)(hp[mi] + k0);
#pragma unroll
      for (int ni = 0; ni < 4; ++ni)
#pragma unroll
        for (int mi = 0; mi < 2; ++mi)
          acc[ni][mi] = __builtin_amdgcn_mfma_f32_16x16x32_bf16(af[ni], bx[mi], acc[ni][mi], 0, 0, 0);
    }
#pragma unroll
    for (int ni = 0; ni < 4; ++ni) {
      const int nb = n0 + ni * 16 + quad * 4;
      floatx4 bb = *(const floatx4*)&b2[nb];
#pragma unroll
      for (int mi = 0; mi < 2; ++mi) {
        s4 h;
#pragma unroll
        for (int r = 0; r < 4; ++r) h[r] = bf16bits(lrelu(acc[ni][mi][r] + bb[r]));
        *(s4*)&H2[(mi * 16 + m16) * H_PITCH + nb] = h;
      }
    }
  }
  __syncthreads();

  // ---------------- layer 3: N=256, K=512, A from LDS H2 ----------------
  {
    const int n0 = wv * 32;
    const u16* wp[2];
#pragma unroll
    for (int ni = 0; ni < 2; ++ni)
      wp[ni] = W3t + (size_t)(n0 + ni * 16 + m16) * 512 + quad * 8;
    const u16* hp[2];
#pragma unroll
    for (int mi = 0; mi < 2; ++mi)
      hp[mi] = H2 + (mi * 16 + m16) * H_PITCH + quad * 8;

    floatx4 acc[2][2];
#pragma unroll
    for (int i = 0; i < 2; i++)
#pragma unroll
      for (int j = 0; j < 2; j++) { floatx4 z = {0.f,0.f,0.f,0.f}; acc[i][j] = z; }

    short8 afn[2];
#pragma unroll
    for (int ni = 0; ni < 2; ++ni) afn[ni] = *(const short8*)wp[ni];

#pragma unroll 1
    for (int k0 = 0; k0 < 512; k0 += 32) {
      short8 af[2];
#pragma unroll
      for (int ni = 0; ni < 2; ++ni) af[ni] = afn[ni];
      if (k0 + 32 < 512) {
#pragma unroll
        for (int ni = 0; ni < 2; ++ni) afn[ni] = *(const short8*)(wp[ni] + k0 + 32);
      }
      short8 bx[2];
#pragma unroll
      for (int mi = 0; mi < 2; ++mi) bx[mi] = *(const short8*)(hp[mi] + k0);
#pragma unroll
      for (int ni = 0; ni < 2; ++ni)
#pragma unroll
        for (int mi = 0; mi < 2; ++mi)
          acc[ni][mi] = __builtin_amdgcn_mfma_f32_16x16x32_bf16(af[ni], bx[mi], acc[ni][mi], 0, 0, 0);
    }

    floatx4 bb[2];
#pragma unroll
    for (int ni = 0; ni < 2; ++ni)
      bb[ni] = *(const floatx4*)&b3[n0 + ni * 16 + quad * 4];

    if (MODE == 1) {
      // stage f32 outputs in LDS (H1 region is dead) + dag ids, then
      // segmented column reduction: one atomic per (dag-run, col).
      if (tid < ROWS)
        dagsL[tid] = (row0 + tid < M) ? dsort[row0 + tid] : -1;
#pragma unroll
      for (int mi = 0; mi < 2; ++mi) {
        const int lr = mi * 16 + m16;
#pragma unroll
        for (int ni = 0; ni < 2; ++ni) {
          floatx4 h;
#pragma unroll
          for (int r = 0; r < 4; ++r) h[r] = lrelu(acc[ni][mi][r] + bb[ni][r]);
          *(floatx4*)&Yl[lr * Y_PITCH + n0 + ni * 16 + quad * 4] = h;
        }
      }
      __syncthreads();
      if (tid < 256) {
        const int col = tid;
        int curd = dagsL[0];
        float a = Yl[col];
        for (int r = 1; r < ROWS; ++r) {
          int d = dagsL[r];           // wave-uniform
          float v = Yl[r * Y_PITCH + col];
          if (d == curd) {
            a += v;
          } else {
            if (curd >= 0) atomicAdd(&segOut[(size_t)curd * 256 + col], a);
            curd = d;
            a = v;
          }
        }
        if (curd >= 0) atomicAdd(&segOut[(size_t)curd * 256 + col], a);
      }
    } else {
#pragma unroll
      for (int mi = 0; mi < 2; ++mi) {
        const int r0 = row0 + mi * 16 + m16;
        if (r0 < M) {
#pragma unroll
          for (int ni = 0; ni < 2; ++ni) {
            floatx4 h;
#pragma unroll
            for (int r = 0; r < 4; ++r) h[r] = lrelu(acc[ni][mi][r] + bb[ni][r]);
            *(floatx4*)&C[(size_t)r0 * 256 + n0 + ni * 16 + quad * 4] = h;
          }
        }
      }
    }
  }
}

// ---------------------------------------------------------------------------
// s2[j] += chunked mask @ g3; grid-parallel + atomic combine.
// ---------------------------------------------------------------------------
__global__ __launch_bounds__(256) void s2_reduce(const float* __restrict__ mask,
                                                 const float* __restrict__ g3,
                                                 float* __restrict__ out,
                                                 int numDags, int outOff) {
  const int j = threadIdx.x;
  const int chunk = (numDags + gridDim.x - 1) / gridDim.x;
  const int d0 = blockIdx.x * chunk;
  const int d1 = min(d0 + chunk, numDags);
  float acc = 0.f;
  for (int d = d0; d < d1; ++d)
    acc += mask[d] * g3[(size_t)d * 256 + j];
  atomicAdd(out + outOff + j, acc);
}

extern "C" void kernel_launch(void* const* d_in, const int* in_sizes, int n_in,
                              void* d_out, int out_size, void* d_ws, size_t ws_size,
                              hipStream_t stream) {
  (void)in_sizes; (void)n_in; (void)ws_size;
  constexpr int N_   = 100000;
  constexpr int IND  = 128;
  constexpr int H1D  = 512;
  constexpr int H2D  = 512;
  constexpr int OUTD = 256;
  constexpr int NDAG = 2000;

  const float* X    = (const float*)d_in[0];
  const int*   dag  = (const int*)d_in[1];
  const float* mask = (const float*)d_in[2];
  const float* W1 = (const float*)d_in[3];
  const float* b1 = (const float*)d_in[4];
  const float* W2 = (const float*)d_in[5];
  const float* b2 = (const float*)d_in[6];
  const float* W3 = (const float*)d_in[7];
  const float* b3 = (const float*)d_in[8];
  const float* W4 = (const float*)d_in[9];
  const float* b4 = (const float*)d_in[10];
  const float* W5 = (const float*)d_in[11];
  const float* b5 = (const float*)d_in[12];
  const float* W6 = (const float*)d_in[13];
  const float* b6 = (const float*)d_in[14];

  char* ws = (char*)d_ws;
  auto alloc = [&](size_t bytes) {
    char* p = ws;
    ws += (bytes + 255) & ~(size_t)255;
    return p;
  };
  u16* W1t = (u16*)alloc((size_t)H1D * IND * 2);
  u16* W2t = (u16*)alloc((size_t)H2D * H1D * 2);
  u16* W3t = (u16*)alloc((size_t)OUTD * H2D * 2);
  u16* W4t = (u16*)alloc((size_t)H1D * OUTD * 2);
  u16* W5t = (u16*)alloc((size_t)H2D * H1D * 2);
  u16* W6t = (u16*)alloc((size_t)OUTD * H2D * 2);
  float* g3   = (float*)alloc((size_t)NDAG * OUTD * 4);
  int* hist   = (int*)alloc((size_t)NDAG * 4);
  int* cursor = (int*)alloc((size_t)NDAG * 4);
  int* perm   = (int*)alloc((size_t)N_ * 4);
  int* dsort  = (int*)alloc((size_t)N_ * 4);

  float* out = (float*)d_out;
  float* s1  = out;                // [2000][256] f32, output 0
  const int s2Off = NDAG * OUTD;   // output 1 offset

  hipFuncSetAttribute(reinterpret_cast<const void*>(&fused3<IND, 1>),
                      hipFuncAttributeMaxDynamicSharedMemorySize, FUSED_LDS);
  hipFuncSetAttribute(reinterpret_cast<const void*>(&fused3<OUTD, 0>),
                      hipFuncAttributeMaxDynamicSharedMemorySize, FUSED_LDS);

  // zero output accumulators + histogram
  hipMemsetAsync(out, 0, (size_t)out_size * 4, stream);
  hipMemsetAsync(hist, 0, (size_t)NDAG * 4, stream);

  // counting sort of nodes by dag id
  hist_kernel<<<(N_ + 255) / 256, 256, 0, stream>>>(dag, hist, N_);
  scan_offsets<<<1, 256, 0, stream>>>(hist, cursor);
  scatter_kernel<<<(N_ + 255) / 256, 256, 0, stream>>>(dag, cursor, perm, dsort, N_);

  // weight transposes+convert
  transpose_f32_bf16<<<dim3(H1D / 32, IND / 32), 256, 0, stream>>>(W1, W1t, IND, H1D);
  transpose_f32_bf16<<<dim3(H2D / 32, H1D / 32), 256, 0, stream>>>(W2, W2t, H1D, H2D);
  transpose_f32_bf16<<<dim3(OUTD / 32, H2D / 32), 256, 0, stream>>>(W3, W3t, H2D, OUTD);
  transpose_f32_bf16<<<dim3(H1D / 32, OUTD / 32), 256, 0, stream>>>(W4, W4t, OUTD, H1D);
  transpose_f32_bf16<<<dim3(H2D / 32, H1D / 32), 256, 0, stream>>>(W5, W5t, H1D, H2D);
  transpose_f32_bf16<<<dim3(OUTD / 32, H2D / 32), 256, 0, stream>>>(W6, W6t, H2D, OUTD);

  // fused node stack + segmented dag reduction into output 0
  fused3<IND, 1><<<(N_ + ROWS - 1) / ROWS, 512, FUSED_LDS, stream>>>(
      X, W1t, W2t, W3t, b1, b2, b3, s1, perm, dsort, nullptr, N_);

  // fused global stack: reads s1 (f32, from d_out), writes g3 (f32)
  fused3<OUTD, 0><<<(NDAG + ROWS - 1) / ROWS, 512, FUSED_LDS, stream>>>(
      s1, W4t, W5t, W6t, b4, b5, b6, nullptr, nullptr, nullptr, g3, NDAG);

  // s2 = mask @ g3 -> output 1 (pre-zeroed)
  s2_reduce<<<20, 256, 0, stream>>>(mask, g3, out, NDAG, s2Off);
}

// Round 6
// 469.598 us; speedup vs baseline: 2.4493x; 1.2714x over previous
//
#include <hip/hip_runtime.h>
#include <hip/hip_bf16.h>

typedef unsigned short u16;
typedef __attribute__((ext_vector_type(8))) short short8;
typedef __attribute__((ext_vector_type(4))) short s4;
typedef __attribute__((ext_vector_type(4))) float floatx4;

__device__ __forceinline__ float lrelu(float x) { return x > 0.f ? x : 0.01f * x; }

__device__ __forceinline__ short bf16bits(float v) {
  __hip_bfloat16 t = __float2bfloat16(v);
  return *reinterpret_cast<short*>(&t);
}

__device__ __forceinline__ short8 pack8(floatx4 x0, floatx4 x1) {
  short8 b;
#pragma unroll
  for (int r = 0; r < 4; ++r) { b[r] = bf16bits(x0[r]); b[4 + r] = bf16bits(x1[r]); }
  return b;
}

__device__ __forceinline__ void gload_lds16(const void* g, void* lds) {
  __builtin_amdgcn_global_load_lds(
      (const __attribute__((address_space(1))) unsigned int*)g,
      (__attribute__((address_space(3))) unsigned int*)lds, 16, 0, 0);
}

// ---------------------------------------------------------------------------
// Batched transpose+convert: 6 weights W[K][N] f32 -> Wt[N][K] bf16, 1 launch.
// ---------------------------------------------------------------------------
__global__ __launch_bounds__(256) void transpose_all(
    const float* __restrict__ W1, const float* __restrict__ W2,
    const float* __restrict__ W3, const float* __restrict__ W4,
    const float* __restrict__ W5, const float* __restrict__ W6,
    u16* __restrict__ T1, u16* __restrict__ T2, u16* __restrict__ T3,
    u16* __restrict__ T4, u16* __restrict__ T5, u16* __restrict__ T6) {
  const float* W; u16* T; int K, N;
  switch (blockIdx.z) {
    case 0: W = W1; T = T1; K = 128; N = 512; break;
    case 1: W = W2; T = T2; K = 512; N = 512; break;
    case 2: W = W3; T = T3; K = 512; N = 256; break;
    case 3: W = W4; T = T4; K = 256; N = 512; break;
    case 4: W = W5; T = T5; K = 512; N = 512; break;
    default: W = W6; T = T6; K = 512; N = 256; break;
  }
  if ((int)blockIdx.x >= N / 32 || (int)blockIdx.y >= K / 32) return;
  __shared__ u16 tile[32][33];
  const int tx = threadIdx.x & 31;
  const int ty = threadIdx.x >> 5;
  const int n0 = blockIdx.x * 32;
  const int k0 = blockIdx.y * 32;
  for (int i = ty; i < 32; i += 8)
    tile[i][tx] = (u16)bf16bits(W[(size_t)(k0 + i) * N + n0 + tx]);
  __syncthreads();
  for (int i = ty; i < 32; i += 8)
    T[(size_t)(n0 + i) * K + k0 + tx] = tile[tx][i];
}

// ---------------------------------------------------------------------------
// Counting sort of node ids by dag id (2000 bins).
// ---------------------------------------------------------------------------
__global__ __launch_bounds__(256) void hist_kernel(const int* __restrict__ dag,
                                                   int* __restrict__ hist, int n) {
  int i = blockIdx.x * blockDim.x + threadIdx.x;
  if (i < n) atomicAdd(&hist[dag[i]], 1);
}

__global__ __launch_bounds__(256) void scan_offsets(const int* __restrict__ hist,
                                                    int* __restrict__ cursor) {
  __shared__ int part[256];
  const int t = threadIdx.x;
  const int base = t * 8;
  int loc[8];
  int s = 0;
#pragma unroll
  for (int j = 0; j < 8; ++j) {
    int v = (base + j < 2000) ? hist[base + j] : 0;
    loc[j] = s;
    s += v;
  }
  part[t] = s;
  __syncthreads();
  int val = s;
  for (int off = 1; off < 256; off <<= 1) {
    int tmp = (t >= off) ? part[t - off] : 0;
    __syncthreads();
    val += tmp;
    part[t] = val;
    __syncthreads();
  }
  const int chunkBase = (t == 0) ? 0 : part[t - 1];
#pragma unroll
  for (int j = 0; j < 8; ++j)
    if (base + j < 2000) cursor[base + j] = chunkBase + loc[j];
}

__global__ __launch_bounds__(256) void scatter_kernel(const int* __restrict__ dag,
                                                      int* __restrict__ cursor,
                                                      int* __restrict__ perm,
                                                      int* __restrict__ dsort, int n) {
  int i = blockIdx.x * blockDim.x + threadIdx.x;
  if (i < n) {
    int d = dag[i];
    int p = atomicAdd(&cursor[d], 1);
    perm[p] = i;
    dsort[p] = d;
  }
}

// ---------------------------------------------------------------------------
// Fused 3-layer MLP, 32 rows/block, m97-style global_load_lds weight staging.
// LDS: H1[32][520] + H2[32][520] bf16 (66560 B) + W tile dbuf (65536 B) + dags.
// 1 block/CU. 512 thr = 8 waves; wave wv owns cols [wv*64,..) (L1/L2),
// [wv*32,..) (L3). Swapped-operand MFMA: a=weight rows, b=activation rows.
// D[n][m]: n=quad*4+reg, m=lane&15.
// Staging swizzle: lane -> (row=lane>>2, kq=(sig-(row>>1))&3) so that the
// a-frag ds_read_b128 hits 8 bank-groups x 2-way (free, m136).
// ---------------------------------------------------------------------------
#define ROWS 32
#define H_PITCH 520
#define HBYTES (ROWS * H_PITCH * 2)     // 33280
#define WL_OFF (2 * HBYTES)             // 66560
#define WL_HALF 16384                   // elements (32 KB) per dbuf half
#define DAGS_OFF (WL_OFF + 65536)       // 132096
#define FUSED_LDS (DAGS_OFF + 128)      // 132224
#define Y_PITCH 260

template <int K1, int MODE>
__global__ __launch_bounds__(512, 2) void fused3(
    const float* __restrict__ A0,  // [M][K1] f32
    const u16* __restrict__ W1t,   // [512][K1] bf16
    const u16* __restrict__ W2t,   // [512][512] bf16
    const u16* __restrict__ W3t,   // [256][512] bf16
    const float* __restrict__ b1,
    const float* __restrict__ b2,
    const float* __restrict__ b3,
    float* __restrict__ segOut,
    const int* __restrict__ perm, const int* __restrict__ dsort,
    float* __restrict__ C, int M) {
  extern __shared__ __align__(16) char ldsbuf[];
  u16* H1 = (u16*)ldsbuf;
  u16* H2 = (u16*)(ldsbuf + HBYTES);
  u16* Wl = (u16*)(ldsbuf + WL_OFF);
  float* Yl = (float*)ldsbuf;                 // reuses H1 region (layer-3 epilogue)
  int* dagsL = (int*)(ldsbuf + DAGS_OFF);

  const int tid  = threadIdx.x;
  const int wv   = tid >> 6;
  const int lane = tid & 63;
  const int m16  = lane & 15;
  const int quad = lane >> 4;
  const int row0 = blockIdx.x * ROWS;

  // staging lane mapping (write side)
  const int sr   = lane >> 2;                  // row within 16-row chunk
  const int skq  = ((lane & 3) - (sr >> 1)) & 3;  // k-quarter this lane fetches
  // read-side swizzled sub-offset (elements within a chunk)
  const int sw8  = (m16 * 4 + ((quad + (m16 >> 1)) & 3)) * 8;

  auto stage512 = [&](const u16* Wt, int K, int k0, int sel) {
    u16* base = Wl + sel * WL_HALF;
#pragma unroll
    for (int c = 0; c < 4; ++c) {
      int chunk = wv * 4 + c;
      gload_lds16(Wt + (size_t)(chunk * 16 + sr) * K + k0 + skq * 8,
                  base + chunk * 512);
    }
  };
  auto stage256 = [&](const u16* Wt, int K, int k0, int sel) {
    u16* base = Wl + sel * 8192;
#pragma unroll
    for (int c = 0; c < 2; ++c) {
      int chunk = wv * 2 + c;
      gload_lds16(Wt + (size_t)(chunk * 16 + sr) * K + k0 + skq * 8,
                  base + chunk * 512);
    }
  };

  int grow[2];
#pragma unroll
  for (int mi = 0; mi < 2; ++mi) {
    int r = row0 + mi * 16 + m16;
    r = r < M ? r : (M - 1);
    grow[mi] = (MODE == 1) ? perm[r] : r;
  }
  const float* ap[2];
#pragma unroll
  for (int mi = 0; mi < 2; ++mi) ap[mi] = A0 + (size_t)grow[mi] * K1 + quad * 8;

  // ---------------- layer 1: N=512, K=K1 ----------------
  {
    constexpr int NS1 = K1 / 32;
    // register-prefetch all activation data when small (node stack, K1=128)
    floatx4 xa[(K1 == 128) ? 4 : 1][2][2];
    if constexpr (K1 == 128) {
#pragma unroll
      for (int s = 0; s < 4; ++s)
#pragma unroll
        for (int mi = 0; mi < 2; ++mi) {
          xa[s][mi][0] = *(const floatx4*)(ap[mi] + s * 32);
          xa[s][mi][1] = *(const floatx4*)(ap[mi] + s * 32 + 4);
        }
    }
    stage512(W1t, K1, 0, 0);

    floatx4 acc[4][2];
#pragma unroll
    for (int i = 0; i < 4; i++)
#pragma unroll
      for (int j = 0; j < 2; j++) { floatx4 z = {0.f,0.f,0.f,0.f}; acc[i][j] = z; }

#pragma unroll
    for (int s = 0; s < NS1; ++s) {
      __syncthreads();
      if (s + 1 < NS1) stage512(W1t, K1, (s + 1) * 32, (s + 1) & 1);
      const u16* wb = Wl + (s & 1) * WL_HALF;
      short8 af[4], bx[2];
#pragma unroll
      for (int ni = 0; ni < 4; ++ni)
        af[ni] = *(const short8*)(wb + (wv * 4 + ni) * 512 + sw8);
#pragma unroll
      for (int mi = 0; mi < 2; ++mi) {
        if constexpr (K1 == 128) {
          bx[mi] = pack8(xa[s][mi][0], xa[s][mi][1]);
        } else {
          bx[mi] = pack8(*(const floatx4*)(ap[mi] + s * 32),
                         *(const floatx4*)(ap[mi] + s * 32 + 4));
        }
      }
#pragma unroll
      for (int ni = 0; ni < 4; ++ni)
#pragma unroll
        for (int mi = 0; mi < 2; ++mi)
          acc[ni][mi] = __builtin_amdgcn_mfma_f32_16x16x32_bf16(af[ni], bx[mi], acc[ni][mi], 0, 0, 0);
    }
    const int n0 = wv * 64;
#pragma unroll
    for (int ni = 0; ni < 4; ++ni) {
      const int nb = n0 + ni * 16 + quad * 4;
      floatx4 bb = *(const floatx4*)&b1[nb];
#pragma unroll
      for (int mi = 0; mi < 2; ++mi) {
        s4 h;
#pragma unroll
        for (int r = 0; r < 4; ++r) h[r] = bf16bits(lrelu(acc[ni][mi][r] + bb[r]));
        *(s4*)&H1[(mi * 16 + m16) * H_PITCH + nb] = h;
      }
    }
  }

  // ---------------- layer 2: N=512, K=512, A from LDS H1 ----------------
  {
    stage512(W2t, 512, 0, 0);  // drained by first in-loop barrier (with H1 sync)
    const u16* hp[2];
#pragma unroll
    for (int mi = 0; mi < 2; ++mi)
      hp[mi] = H1 + (mi * 16 + m16) * H_PITCH + quad * 8;

    floatx4 acc[4][2];
#pragma unroll
    for (int i = 0; i < 4; i++)
#pragma unroll
      for (int j = 0; j < 2; j++) { floatx4 z = {0.f,0.f,0.f,0.f}; acc[i][j] = z; }

    for (int s = 0; s < 16; ++s) {
      __syncthreads();
      if (s < 15) stage512(W2t, 512, (s + 1) * 32, (s + 1) & 1);
      const u16* wb = Wl + (s & 1) * WL_HALF;
      short8 af[4], bx[2];
#pragma unroll
      for (int ni = 0; ni < 4; ++ni)
        af[ni] = *(const short8*)(wb + (wv * 4 + ni) * 512 + sw8);
#pragma unroll
      for (int mi = 0; mi < 2; ++mi) bx[mi] = *(const short8*)(hp[mi] + s * 32);
#pragma unroll
      for (int ni = 0; ni < 4; ++ni)
#pragma unroll
        for (int mi = 0; mi < 2; ++mi)
          acc[ni][mi] = __builtin_amdgcn_mfma_f32_16x16x32_bf16(af[ni], bx[mi], acc[ni][mi], 0, 0, 0);
    }
    const int n0 = wv * 64;
#pragma unroll
    for (int ni = 0; ni < 4; ++ni) {
      const int nb = n0 + ni * 16 + quad * 4;
      floatx4 bb = *(const floatx4*)&b2[nb];
#pragma unroll
      for (int mi = 0; mi < 2; ++mi) {
        s4 h;
#pragma unroll
        for (int r = 0; r < 4; ++r) h[r] = bf16bits(lrelu(acc[ni][mi][r] + bb[r]));
        *(s4*)&H2[(mi * 16 + m16) * H_PITCH + nb] = h;
      }
    }
  }

  // ---------------- layer 3: N=256, K=512, A from LDS H2 ----------------
  {
    stage256(W3t, 512, 0, 0);
    const u16* hp[2];
#pragma unroll
    for (int mi = 0; mi < 2; ++mi)
      hp[mi] = H2 + (mi * 16 + m16) * H_PITCH + quad * 8;

    floatx4 acc[2][2];
#pragma unroll
    for (int i = 0; i < 2; i++)
#pragma unroll
      for (int j = 0; j < 2; j++) { floatx4 z = {0.f,0.f,0.f,0.f}; acc[i][j] = z; }

    for (int s = 0; s < 16; ++s) {
      __syncthreads();
      if (s < 15) stage256(W3t, 512, (s + 1) * 32, (s + 1) & 1);
      const u16* wb = Wl + (s & 1) * 8192;
      short8 af[2], bx[2];
#pragma unroll
      for (int ni = 0; ni < 2; ++ni)
        af[ni] = *(const short8*)(wb + (wv * 2 + ni) * 512 + sw8);
#pragma unroll
      for (int mi = 0; mi < 2; ++mi) bx[mi] = *(const short8*)(hp[mi] + s * 32);
#pragma unroll
      for (int ni = 0; ni < 2; ++ni)
#pragma unroll
        for (int mi = 0; mi < 2; ++mi)
          acc[ni][mi] = __builtin_amdgcn_mfma_f32_16x16x32_bf16(af[ni], bx[mi], acc[ni][mi], 0, 0, 0);
    }

    const int n0 = wv * 32;
    floatx4 bb[2];
#pragma unroll
    for (int ni = 0; ni < 2; ++ni)
      bb[ni] = *(const floatx4*)&b3[n0 + ni * 16 + quad * 4];

    if (MODE == 1) {
      if (tid < ROWS)
        dagsL[tid] = (row0 + tid < M) ? dsort[row0 + tid] : -1;
#pragma unroll
      for (int mi = 0; mi < 2; ++mi) {
        const int lr = mi * 16 + m16;
#pragma unroll
        for (int ni = 0; ni < 2; ++ni) {
          floatx4 h;
#pragma unroll
          for (int r = 0; r < 4; ++r) h[r] = lrelu(acc[ni][mi][r] + bb[ni][r]);
          *(floatx4*)&Yl[lr * Y_PITCH + n0 + ni * 16 + quad * 4] = h;
        }
      }
      __syncthreads();
      if (tid < 256) {
        const int col = tid;
        int curd = dagsL[0];
        float a = Yl[col];
        for (int r = 1; r < ROWS; ++r) {
          int d = dagsL[r];  // wave-uniform
          float v = Yl[r * Y_PITCH + col];
          if (d == curd) {
            a += v;
          } else {
            if (curd >= 0) atomicAdd(&segOut[(size_t)curd * 256 + col], a);
            curd = d;
            a = v;
          }
        }
        if (curd >= 0) atomicAdd(&segOut[(size_t)curd * 256 + col], a);
      }
    } else {
#pragma unroll
      for (int mi = 0; mi < 2; ++mi) {
        const int r0 = row0 + mi * 16 + m16;
        if (r0 < M) {
#pragma unroll
          for (int ni = 0; ni < 2; ++ni) {
            floatx4 h;
#pragma unroll
            for (int r = 0; r < 4; ++r) h[r] = lrelu(acc[ni][mi][r] + bb[ni][r]);
            *(floatx4*)&C[(size_t)r0 * 256 + n0 + ni * 16 + quad * 4] = h;
          }
        }
      }
    }
  }
}

// ---------------------------------------------------------------------------
// s2[j] += chunked mask @ g3; 250 blocks x 8 dags, atomic combine.
// ---------------------------------------------------------------------------
__global__ __launch_bounds__(256) void s2_reduce(const float* __restrict__ mask,
                                                 const float* __restrict__ g3,
                                                 float* __restrict__ out,
                                                 int numDags, int outOff) {
  const int j = threadIdx.x;
  const int chunk = (numDags + gridDim.x - 1) / gridDim.x;
  const int d0 = blockIdx.x * chunk;
  const int d1 = min(d0 + chunk, numDags);
  float acc = 0.f;
  for (int d = d0; d < d1; ++d)
    acc += mask[d] * g3[(size_t)d * 256 + j];
  atomicAdd(out + outOff + j, acc);
}

extern "C" void kernel_launch(void* const* d_in, const int* in_sizes, int n_in,
                              void* d_out, int out_size, void* d_ws, size_t ws_size,
                              hipStream_t stream) {
  (void)in_sizes; (void)n_in; (void)ws_size;
  constexpr int N_   = 100000;
  constexpr int IND  = 128;
  constexpr int H1D  = 512;
  constexpr int H2D  = 512;
  constexpr int OUTD = 256;
  constexpr int NDAG = 2000;

  const float* X    = (const float*)d_in[0];
  const int*   dag  = (const int*)d_in[1];
  const float* mask = (const float*)d_in[2];
  const float* W1 = (const float*)d_in[3];
  const float* b1 = (const float*)d_in[4];
  const float* W2 = (const float*)d_in[5];
  const float* b2 = (const float*)d_in[6];
  const float* W3 = (const float*)d_in[7];
  const float* b3 = (const float*)d_in[8];
  const float* W4 = (const float*)d_in[9];
  const float* b4 = (const float*)d_in[10];
  const float* W5 = (const float*)d_in[11];
  const float* b5 = (const float*)d_in[12];
  const float* W6 = (const float*)d_in[13];
  const float* b6 = (const float*)d_in[14];

  char* ws = (char*)d_ws;
  auto alloc = [&](size_t bytes) {
    char* p = ws;
    ws += (bytes + 255) & ~(size_t)255;
    return p;
  };
  u16* W1t = (u16*)alloc((size_t)H1D * IND * 2);
  u16* W2t = (u16*)alloc((size_t)H2D * H1D * 2);
  u16* W3t = (u16*)alloc((size_t)OUTD * H2D * 2);
  u16* W4t = (u16*)alloc((size_t)H1D * OUTD * 2);
  u16* W5t = (u16*)alloc((size_t)H2D * H1D * 2);
  u16* W6t = (u16*)alloc((size_t)OUTD * H2D * 2);
  float* g3   = (float*)alloc((size_t)NDAG * OUTD * 4);
  int* hist   = (int*)alloc((size_t)NDAG * 4);
  int* cursor = (int*)alloc((size_t)NDAG * 4);
  int* perm   = (int*)alloc((size_t)N_ * 4);
  int* dsort  = (int*)alloc((size_t)N_ * 4);

  float* out = (float*)d_out;
  float* s1  = out;                // [2000][256] f32, output 0
  const int s2Off = NDAG * OUTD;   // output 1 offset

  hipFuncSetAttribute(reinterpret_cast<const void*>(&fused3<IND, 1>),
                      hipFuncAttributeMaxDynamicSharedMemorySize, FUSED_LDS);
  hipFuncSetAttribute(reinterpret_cast<const void*>(&fused3<OUTD, 0>),
                      hipFuncAttributeMaxDynamicSharedMemorySize, FUSED_LDS);

  // zero output accumulators + histogram
  hipMemsetAsync(out, 0, (size_t)out_size * 4, stream);
  hipMemsetAsync(hist, 0, (size_t)NDAG * 4, stream);

  // counting sort of nodes by dag id
  hist_kernel<<<(N_ + 255) / 256, 256, 0, stream>>>(dag, hist, N_);
  scan_offsets<<<1, 256, 0, stream>>>(hist, cursor);
  scatter_kernel<<<(N_ + 255) / 256, 256, 0, stream>>>(dag, cursor, perm, dsort, N_);

  // all 6 weight transposes in one launch
  transpose_all<<<dim3(16, 16, 6), 256, 0, stream>>>(W1, W2, W3, W4, W5, W6,
                                                     W1t, W2t, W3t, W4t, W5t, W6t);

  // fused node stack + segmented dag reduction into output 0
  fused3<IND, 1><<<(N_ + ROWS - 1) / ROWS, 512, FUSED_LDS, stream>>>(
      X, W1t, W2t, W3t, b1, b2, b3, s1, perm, dsort, nullptr, N_);

  // fused global stack: reads s1 (f32, from d_out), writes g3 (f32)
  fused3<OUTD, 0><<<(NDAG + ROWS - 1) / ROWS, 512, FUSED_LDS, stream>>>(
      s1, W4t, W5t, W6t, b4, b5, b6, nullptr, nullptr, nullptr, g3, NDAG);

  // s2 = mask @ g3 -> output 1 (pre-zeroed)
  s2_reduce<<<250, 256, 0, stream>>>(mask, g3, out, NDAG, s2Off);
}